// Round 2
// baseline (187.047 us; speedup 1.0000x reference)
//
#include <hip/hip_runtime.h>
#include <hip/hip_bf16.h>
#include <stdint.h>

#define K_DIM 512
#define N_DIM 512
#define BM 64

typedef __bf16 bf16x8 __attribute__((ext_vector_type(8)));
typedef float floatx4 __attribute__((ext_vector_type(4)));

__device__ __forceinline__ bf16x8 cvt8(float4 a, float4 b) {
    bf16x8 r;
    r[0] = (__bf16)a.x; r[1] = (__bf16)a.y; r[2] = (__bf16)a.z; r[3] = (__bf16)a.w;
    r[4] = (__bf16)b.x; r[5] = (__bf16)b.y; r[6] = (__bf16)b.z; r[7] = (__bf16)b.w;
    return r;
}

// Pre-convert W [N,K] fp32 -> fragment-linear bf16:
// wf[((nt*16+kc)*64 + lane)*8 + j] = W[nt*16+(lane&15)][kc*32+(lane>>4)*8+j]
__global__ __launch_bounds__(512) void wconv_kernel(const float* __restrict__ w,
                                                    __bf16* __restrict__ wf) {
    int t = blockIdx.x * 512 + threadIdx.x;     // 0..32767
    int lane = t & 63, slot = t >> 6;           // slot = nt*16+kc
    int n = ((slot >> 4) << 4) + (lane & 15);
    int k = ((slot & 15) << 5) + ((lane >> 4) << 3);
    const float* src = w + (size_t)n * K_DIM + k;
    float4 f0 = *(const float4*)src;
    float4 f1 = *(const float4*)(src + 4);
    *(bf16x8*)(wf + (size_t)t * 8) = cvt8(f0, f1);
}

template <bool USE_WF>
__global__ __launch_bounds__(512, 4) void gemm_kernel(
    const float* __restrict__ x, const float* __restrict__ xscale,
    const __bf16* __restrict__ wf, const float* __restrict__ w,
    const float* __restrict__ wscale, float* __restrict__ out)
{
    // fragment-linear A tile: [idx = rt*16+kc][lane][8 bf16]  (64 KiB)
    __shared__ __bf16 lds[BM * K_DIM];
    const int t = threadIdx.x;
    const int lane = t & 63;
    const int wid = t >> 6;                  // 0..7
    const int rowb = blockIdx.x * BM;

    // ---- stage x rows into LDS as bf16 fragments (each byte of x read once) ----
    #pragma unroll
    for (int p = 0; p < 8; ++p) {
        int idx = p * 8 + wid;               // rt*16+kc, 0..63
        int rt = idx >> 4, kc = idx & 15;
        int row = (rt << 4) + (lane & 15);
        int k = (kc << 5) + ((lane >> 4) << 3);
        const float* src = x + (size_t)(rowb + row) * K_DIM + k;
        float4 f0 = *(const float4*)src;
        float4 f1 = *(const float4*)(src + 4);
        *(bf16x8*)&lds[idx * 512 + lane * 8] = cvt8(f0, f1);
    }
    __syncthreads();

    // ---- compute: wave wid owns cols [wid*64, wid*64+64) ----
    const int colb = wid * 64;
    floatx4 acc[4][4];
    #pragma unroll
    for (int i = 0; i < 4; ++i)
        #pragma unroll
        for (int j = 0; j < 4; ++j) acc[i][j] = (floatx4)0.f;

    for (int kc = 0; kc < 16; ++kc) {
        bf16x8 ax[4];
        #pragma unroll
        for (int rt = 0; rt < 4; ++rt)
            ax[rt] = *(const bf16x8*)&lds[((rt << 4) + kc) * 512 + lane * 8];
        #pragma unroll
        for (int nt = 0; nt < 4; ++nt) {
            bf16x8 bw;
            if (USE_WF) {
                int ntg = (wid << 2) + nt;
                bw = *(const bf16x8*)(wf + (size_t)(((ntg << 4) + kc) * 64 + lane) * 8);
            } else {
                int n = colb + (nt << 4) + (lane & 15);
                int k = (kc << 5) + ((lane >> 4) << 3);
                const float* src = w + (size_t)n * K_DIM + k;
                float4 f0 = *(const float4*)src;
                float4 f1 = *(const float4*)(src + 4);
                bw = cvt8(f0, f1);
            }
            // D = W_frag x X_frag -> D holds out^T: row=(lane>>4)*4+reg -> n, col=lane&15 -> m
            #pragma unroll
            for (int rt = 0; rt < 4; ++rt)
                acc[rt][nt] = __builtin_amdgcn_mfma_f32_16x16x32_bf16(bw, ax[rt], acc[rt][nt], 0, 0, 0);
        }
    }

    // ---- epilogue: dequant scale, fp32 float4 stores (4 consecutive n per lane) ----
    #pragma unroll
    for (int rt = 0; rt < 4; ++rt) {
        int m = rowb + (rt << 4) + (lane & 15);
        float xs = xscale[m];
        #pragma unroll
        for (int nt = 0; nt < 4; ++nt) {
            int nb = colb + (nt << 4) + ((lane >> 4) << 2);
            float4 wsc = *(const float4*)(wscale + nb);
            floatx4 a = acc[rt][nt];
            float4 o;
            o.x = a[0] * xs * wsc.x;
            o.y = a[1] * xs * wsc.y;
            o.z = a[2] * xs * wsc.z;
            o.w = a[3] * xs * wsc.w;
            *(float4*)(out + (size_t)m * N_DIM + nb) = o;
        }
    }
}

extern "C" void kernel_launch(void* const* d_in, const int* in_sizes, int n_in,
                              void* d_out, int out_size, void* d_ws, size_t ws_size,
                              hipStream_t stream) {
    const float* x      = (const float*)d_in[0];
    const float* xscale = (const float*)d_in[1];
    const float* w      = (const float*)d_in[2];
    const float* wscale = (const float*)d_in[3];
    float* out          = (float*)d_out;

    const int M = in_sizes[0] / K_DIM;       // 131072
    const int grid = M / BM;                 // 2048

    if (ws_size >= (size_t)(N_DIM * K_DIM * sizeof(unsigned short))) {
        __bf16* wf = (__bf16*)d_ws;
        wconv_kernel<<<dim3(64), dim3(512), 0, stream>>>(w, wf);
        gemm_kernel<true><<<dim3(grid), dim3(512), 0, stream>>>(x, xscale, wf, w, wscale, out);
    } else {
        gemm_kernel<false><<<dim3(grid), dim3(512), 0, stream>>>(x, xscale, nullptr, w, wscale, out);
    }
}